// Round 5
// baseline (815.039 us; speedup 1.0000x reference)
//
#include <hip/hip_runtime.h>
#include <math.h>

#define DEV __device__ __forceinline__

typedef __attribute__((ext_vector_type(8))) short bf16x8;
typedef __attribute__((ext_vector_type(4))) float f32x4;

DEV short f2bf(float v) {
    union { float f; unsigned u; } c; c.f = v;
    unsigned r = c.u + 0x7fffu + ((c.u >> 16) & 1u);   // RNE
    return (short)(r >> 16);
}
DEV float bf2f(short s) {
    return __uint_as_float(((unsigned)(unsigned short)s) << 16);
}

// ===========================================================================
// Weight packing: W [KIN][NOUT] f32 (optionally minus Wsub) -> bf16 MFMA-B
// fragments. layout: out[ks*(NOUT*32) + n*32 + kg*8 + i] = W[ks*32+kg*8+i][n]
// ===========================================================================
#define NPACK 20
struct PackJobs {
    const float* W[NPACK];
    const float* Wsub[NPACK];
    int KIN[NPACK];
    int NOUT[NPACK];
    int end[NPACK];   // cumulative element counts
};

__global__ __launch_bounds__(256)
void pack_all(PackJobs j, short* __restrict__ out, int total)
{
    const int idx = blockIdx.x * 256 + threadIdx.x;
    if (idx >= total) return;
    int job = 0;
    while (idx >= j.end[job]) ++job;
    const int base = job ? j.end[job - 1] : 0;
    const int w = idx - base;
    const int nout = j.NOUT[job];
    const int per_ks = nout * 32;
    const int ks = w / per_ks;
    const int r  = w - ks * per_ks;
    const int n  = r >> 5;
    const int kg = (r >> 3) & 3;
    const int i  = r & 7;
    const int k  = ks * 32 + kg * 8 + i;
    float val = 0.0f;
    if (k < j.KIN[job]) {
        val = j.W[job][(size_t)k * nout + n];
        if (j.Wsub[job]) val -= j.Wsub[job][(size_t)k * nout + n];
    }
    out[idx] = f2bf(val);
}

// ===========================================================================
// Sorting by dst: histogram -> single-block scan -> scatter
// ===========================================================================
__global__ __launch_bounds__(256)
void hist_kernel(const int* __restrict__ dst, int* __restrict__ cnt, int E)
{
    const int e = blockIdx.x * 256 + threadIdx.x;
    if (e < E) atomicAdd(&cnt[dst[e]], 1);
}

__global__ __launch_bounds__(1024)
void scan_kernel(int* __restrict__ cnt, int NB)
{
    __shared__ int part[1024];
    const int t = threadIdx.x;
    const int CH = (NB + 1023) >> 10;
    const int base = t * CH;
    int s = 0;
    for (int k = 0; k < CH; ++k) { const int i = base + k; if (i < NB) s += cnt[i]; }
    part[t] = s;
    __syncthreads();
    for (int off = 1; off < 1024; off <<= 1) {
        const int add = (t >= off) ? part[t - off] : 0;
        __syncthreads();
        part[t] += add;
        __syncthreads();
    }
    int run = part[t] - s;
    for (int k = 0; k < CH; ++k) {
        const int i = base + k;
        if (i < NB) { const int c = cnt[i]; cnt[i] = run; run += c; }
    }
}

__global__ __launch_bounds__(256)
void scatter_kernel(const int* __restrict__ src, const int* __restrict__ dst,
                    const float* __restrict__ ea, int* __restrict__ cursor,
                    int* __restrict__ sSrc, int* __restrict__ sDst,
                    float* __restrict__ eaS, int E)
{
    const int e = blockIdx.x * 256 + threadIdx.x;
    if (e >= E) return;
    const int d = dst[e];
    const int p = atomicAdd(&cursor[d], 1);
    sSrc[p] = src[e];
    sDst[p] = d;
    ((float4*)eaS)[p] = ((const float4*)ea)[e];
}

// ===========================================================================
// MFMA GEMM over an LDS row-tile: one wave computes 16 rows x 128 cols.
// ===========================================================================
template<int KP, int FSTR, int NOUT, bool BIAS>
DEV void mfma_gemm(const short* aLds, const short* __restrict__ Wpk,
                   const float* __restrict__ b, int row0, int c0, int lane,
                   f32x4 (&acc)[8])
{
    const int l15 = lane & 15;
    const int lg  = lane >> 4;
#pragma unroll
    for (int f = 0; f < 8; ++f) {
        if (BIAS) {
            const float bv = b[c0 + f * 16 + l15];
            acc[f] = (f32x4){bv, bv, bv, bv};
        } else {
            acc[f] = (f32x4){0.f, 0.f, 0.f, 0.f};
        }
    }
    const short* arow  = aLds + (row0 + l15) * FSTR + lg * 8;
    const short* wbase = Wpk + (size_t)(c0 + l15) * 32 + lg * 8;
#pragma unroll
    for (int ks = 0; ks < KP / 32; ++ks) {
        const bf16x8 av = *(const bf16x8*)(arow + ks * 32);
        const short* wp = wbase + (size_t)ks * NOUT * 32;
#pragma unroll
        for (int f = 0; f < 8; ++f) {
            const bf16x8 bv = *(const bf16x8*)(wp + f * 512);
            acc[f] = __builtin_amdgcn_mfma_f32_16x16x32_bf16(av, bv, acc[f], 0, 0, 0);
        }
    }
}

// relu(acc [+ lds]) -> packed bf16 rows in LDS
template<int OSTR, bool ADDLDS>
DEV void pack_relu(const f32x4 (&acc)[8], short* out, int row0, int c0, int lane)
{
    const int l15 = lane & 15;
    const int lg  = lane >> 4;
#pragma unroll
    for (int f = 0; f < 8; ++f)
#pragma unroll
        for (int i = 0; i < 4; ++i) {
            const int row = row0 + lg * 4 + i;
            const int col = c0 + f * 16 + l15;
            float vv = acc[f][i];
            if (ADDLDS) vv += bf2f(out[row * OSTR + col]);
            vv = fmaxf(vv, 0.0f);
            const float o = __shfl_xor(vv, 1);
            if (!(lane & 1)) {
                const unsigned pk = ((unsigned)(unsigned short)f2bf(o) << 16) |
                                    (unsigned)(unsigned short)f2bf(vv);
                *(unsigned*)&out[row * OSTR + col] = pk;
            }
        }
}

// acc -> bf16 global rows (paired 4-byte stores)
DEV void store_bf16(const f32x4 (&acc)[8], short* __restrict__ out,
                    int n0, int wave, int lane, int N)
{
    const int l15 = lane & 15;
    const int lg  = lane >> 4;
#pragma unroll
    for (int f = 0; f < 8; ++f)
#pragma unroll
        for (int i = 0; i < 4; ++i) {
            const float vv = acc[f][i];
            const float o = __shfl_xor(vv, 1);
            if (!(lane & 1)) {
                const unsigned pk = ((unsigned)(unsigned short)f2bf(o) << 16) |
                                    (unsigned)(unsigned short)f2bf(vv);
                const int n = n0 + wave * 16 + lg * 4 + i;
                if (n < N)
                    *(unsigned*)&out[(size_t)n * 128 + f * 16 + l15] = pk;
            }
        }
}

// ===========================================================================
// Per-node precompute: u = x@(W1a-W1b)+b1 (bf16), v = x@W1b (bf16), sq=||x||^2
// ===========================================================================
template<int FIN, int FSTR>
__global__ __launch_bounds__(256)
void uv_pre(const float* __restrict__ xin,
            const short* __restrict__ Wd, const float* __restrict__ b1,
            const short* __restrict__ Wb,
            short* __restrict__ uB, short* __restrict__ vB,
            float* __restrict__ sq, int N)
{
    __shared__ __align__(16) short feat[64 * FSTR];
    const int tid = threadIdx.x, lane = tid & 63, wave = tid >> 6;
    const int n0 = blockIdx.x * 64;
    {
        const int r = tid >> 2, s = tid & 3, n = n0 + r;
        short* frow = feat + r * FSTR;
        if (n < N) {
            const float4* xr = (const float4*)(xin + (size_t)n * FIN);
            float ss = 0.f;
#pragma unroll
            for (int d4 = s; d4 < FIN / 4; d4 += 4) {
                const float4 a = xr[d4];
                ss += a.x * a.x + a.y * a.y + a.z * a.z + a.w * a.w;
                *(short4*)(frow + d4 * 4) =
                    make_short4(f2bf(a.x), f2bf(a.y), f2bf(a.z), f2bf(a.w));
            }
            ss += __shfl_xor(ss, 1); ss += __shfl_xor(ss, 2);
            if (s == 0) sq[n] = ss;
        } else {
            for (int d = s * 4; d < FIN; d += 16) *(short4*)(frow + d) = make_short4(0, 0, 0, 0);
        }
    }
    __syncthreads();
    f32x4 acc[8];
    mfma_gemm<FIN, FSTR, 128, true>(feat, Wd, b1, wave * 16, 0, lane, acc);
    store_bf16(acc, uB, n0, wave, lane, N);
    mfma_gemm<FIN, FSTR, 128, false>(feat, Wb, nullptr, wave * 16, 0, lane, acc);
    store_bf16(acc, vB, n0, wave, lane, N);
}

// ===========================================================================
// Edge conv: 64 edges/block, 4 waves, sorted-by-dst edges, XCD-chunk swizzle.
// feat = [p(FIN), e1, e2, ea(4), 0-pad] (KPP);  uv = u[dst]+v[src] staged bf16
// h1 = relu(feat@W1ext + uv);  m = relu(h1@W2 + b2);  run-max -> atomicMax.
// ===========================================================================
template<int FIN, int KPP, int FSTR>
__global__ __launch_bounds__(256)
void edge_conv3(const float* __restrict__ x,
                const int* __restrict__ sSrc, const int* __restrict__ sDst,
                const float* __restrict__ eaS, const float* __restrict__ sq,
                const short* __restrict__ uB, const short* __restrict__ vB,
                const short* __restrict__ W1pk, const short* __restrict__ W2pk,
                const float* __restrict__ b2,
                float* __restrict__ agg, int E, int swzQ, int swzR)
{
    constexpr int H1STR = 136;
    __shared__ __align__(16) short sh[64 * FSTR + 64 * H1STR];
    __shared__ int dstv[64];
    short* feat = sh;
    short* h1s  = sh + 64 * FSTR;
    const int tid = threadIdx.x, lane = tid & 63, wave = tid >> 6;
    int bid = blockIdx.x;
    {   // bijective XCD-chunk swizzle (m204)
        const int xcd = bid & 7, idx = bid >> 3;
        bid = (xcd < swzR ? xcd * (swzQ + 1)
                          : swzR * (swzQ + 1) + (xcd - swzR) * swzQ) + idx;
    }
    const int e0 = bid * 64;

    // ---- stage 1: p features + scalars + uv row (4 threads per edge) ----
    {
        const int r = tid >> 2, s = tid & 3, e = e0 + r;
        short* frow = feat + r * FSTR;
        short* urow = h1s + r * H1STR;
        if (e < E) {
            const int si = sSrc[e], di = sDst[e];
            if (s == 0) dstv[r] = di;
            const float4* xs = (const float4*)(x + (size_t)si * FIN);
            const float4* xd = (const float4*)(x + (size_t)di * FIN);
            float sp = 0.f;
#pragma unroll
            for (int d4 = s; d4 < FIN / 4; d4 += 4) {
                const float4 a = xs[d4], b = xd[d4];
                const float px = a.x * b.x, py = a.y * b.y, pz = a.z * b.z, pw = a.w * b.w;
                sp += px + py + pz + pw;
                *(short4*)(frow + d4 * 4) =
                    make_short4(f2bf(px), f2bf(py), f2bf(pz), f2bf(pw));
            }
            sp += __shfl_xor(sp, 1); sp += __shfl_xor(sp, 2);
            const float e2v = sp;
            if (s == 0) {
                const float e1v = sqrtf(fmaxf(sq[si] + sq[di] - 2.f * e2v, 0.f));
                *(short2*)(frow + FIN) = make_short2(f2bf(e1v), f2bf(e2v));
            }
            if (s == 1) {
                const float4 ea4 = *(const float4*)(eaS + (size_t)e * 4);
                *(short2*)(frow + FIN + 2) = make_short2(f2bf(ea4.x), f2bf(ea4.y));
                *(short2*)(frow + FIN + 4) = make_short2(f2bf(ea4.z), f2bf(ea4.w));
            }
            for (int d = FIN + 6 + s; d < KPP; d += 4) frow[d] = 0;
            // uv = u[dst] + v[src] (bf16 in, bf16 out)
            const short4* ud = (const short4*)(uB + (size_t)di * 128);
            const short4* vs = (const short4*)(vB + (size_t)si * 128);
#pragma unroll
            for (int d4 = s; d4 < 32; d4 += 4) {
                const short4 uu = ud[d4], vv = vs[d4];
                const float o0 = bf2f(uu.x) + bf2f(vv.x);
                const float o1 = bf2f(uu.y) + bf2f(vv.y);
                const float o2 = bf2f(uu.z) + bf2f(vv.z);
                const float o3 = bf2f(uu.w) + bf2f(vv.w);
                *(short4*)(urow + d4 * 4) =
                    make_short4(f2bf(o0), f2bf(o1), f2bf(o2), f2bf(o3));
            }
        } else {
            if (s == 0) dstv[r] = -1;
            for (int d = s * 4; d < KPP; d += 16) *(short4*)(frow + d) = make_short4(0, 0, 0, 0);
            for (int d = s * 4; d < 128; d += 16) *(short4*)(urow + d) = make_short4(0, 0, 0, 0);
        }
    }
    __syncthreads();

    f32x4 acc[8];
    // ---- stage 2: h1 = relu(feat@W1ext + uv) ----
    mfma_gemm<KPP, FSTR, 128, false>(feat, W1pk, nullptr, wave * 16, 0, lane, acc);
    pack_relu<H1STR, true>(acc, h1s, wave * 16, 0, lane);
    __syncthreads();
    // ---- stage 3: m = relu(h1@W2 + b2) ----
    mfma_gemm<128, H1STR, 128, true>(h1s, W2pk, b2, wave * 16, 0, lane, acc);
    __syncthreads();
    short* mbuf = sh;                     // [64][132] bf16 (reuses feat region)
    pack_relu<132, false>(acc, mbuf, wave * 16, 0, lane);
    __syncthreads();

    // ---- stage 4: run-max over sorted dst ----
    {
        const int c  = tid >> 1;
        const int rh = tid & 1;
        int cur = -1;
        float mx = 0.0f;
#pragma unroll 4
        for (int i2 = 0; i2 < 32; ++i2) {
            const int row = rh * 32 + i2;
            const int d = dstv[row];
            const float val = bf2f(mbuf[row * 132 + c]);
            if (d != cur) {
                if (cur >= 0)
                    atomicMax((int*)agg + (size_t)cur * 128 + c, __float_as_int(mx));
                cur = d;
                mx = val;
            } else {
                mx = fmaxf(mx, val);
            }
        }
        if (cur >= 0)
            atomicMax((int*)agg + (size_t)cur * 128 + c, __float_as_int(mx));
    }
}

// ===========================================================================
// Node MLP (MFMA): y = relu(relu([x,agg]@W1+b1)@W2+b2) (+x if RES).
// ===========================================================================
template<int FIN, int KP, int FSTR, bool RES>
__global__ __launch_bounds__(256)
void node_mfma(const float* __restrict__ xin, const float* __restrict__ agg,
               const short* __restrict__ W1pk, const float* __restrict__ b1,
               const short* __restrict__ W2pk, const float* __restrict__ b2,
               float* __restrict__ out, int N)
{
    constexpr int H1STR = 136;
    __shared__ __align__(16) short sh[64 * FSTR + 64 * H1STR];
    short* feat = sh;
    short* h1s  = sh + 64 * FSTR;
    const int tid = threadIdx.x, lane = tid & 63, wave = tid >> 6;
    const int n0 = blockIdx.x * 64;

    {
        const int r = tid >> 2, s = tid & 3, n = n0 + r;
        short* frow = feat + r * FSTR;
        if (n < N) {
            const float4* xr = (const float4*)(xin + (size_t)n * FIN);
            const float4* ar = (const float4*)(agg + (size_t)n * 128);
#pragma unroll
            for (int d4 = s; d4 < FIN / 4; d4 += 4) {
                const float4 v = xr[d4];
                *(short4*)(frow + d4 * 4) = make_short4(f2bf(v.x), f2bf(v.y), f2bf(v.z), f2bf(v.w));
            }
#pragma unroll
            for (int d4 = s; d4 < 32; d4 += 4) {
                const float4 v = ar[d4];
                *(short4*)(frow + FIN + d4 * 4) = make_short4(f2bf(v.x), f2bf(v.y), f2bf(v.z), f2bf(v.w));
            }
        } else {
            for (int d = s * 4; d < KP; d += 16) *(short4*)(frow + d) = make_short4(0, 0, 0, 0);
        }
    }
    __syncthreads();

    f32x4 acc[8];
    mfma_gemm<KP, FSTR, 128, true>(feat, W1pk, b1, wave * 16, 0, lane, acc);
    pack_relu<H1STR, false>(acc, h1s, wave * 16, 0, lane);
    __syncthreads();
    mfma_gemm<128, H1STR, 128, true>(h1s, W2pk, b2, wave * 16, 0, lane, acc);
    {
        const int l15 = lane & 15, lg = lane >> 4;
#pragma unroll
        for (int f = 0; f < 8; ++f)
#pragma unroll
            for (int i = 0; i < 4; ++i) {
                const int n = n0 + wave * 16 + lg * 4 + i;
                if (n < N) {
                    const int c = f * 16 + l15;
                    float v = fmaxf(acc[f][i], 0.0f);
                    if (RES) v += xin[(size_t)n * 128 + c];
                    out[(size_t)n * 128 + c] = v;
                }
            }
    }
}

// ===========================================================================
// Fusion MLP (MFMA): out = relu(relu([x1,x2,x3]@W1+b1)@W2+b2).
// ===========================================================================
__global__ __launch_bounds__(128)
void fusion_mfma(const float* __restrict__ x1, const float* __restrict__ x2,
                 const float* __restrict__ x3,
                 const short* __restrict__ W1pk, const float* __restrict__ b1,
                 const short* __restrict__ W2pk, const float* __restrict__ b2,
                 float* __restrict__ out, int N)
{
    constexpr int FSTR = 392;
    constexpr int H1STR = 264;
    __shared__ __align__(16) short sh[32 * FSTR + 32 * H1STR];
    short* feat = sh;
    short* h1s  = sh + 32 * FSTR;
    const int tid = threadIdx.x, lane = tid & 63, wave = tid >> 6;
    const int n0 = blockIdx.x * 32;

    {
        const int r = tid >> 2, s = tid & 3, n = n0 + r;
        short* frow = feat + r * FSTR;
        if (n < N) {
            const float4* a1 = (const float4*)(x1 + (size_t)n * 128);
            const float4* a2 = (const float4*)(x2 + (size_t)n * 128);
            const float4* a3 = (const float4*)(x3 + (size_t)n * 128);
#pragma unroll
            for (int d4 = s; d4 < 32; d4 += 4) {
                const float4 v1 = a1[d4], v2 = a2[d4], v3 = a3[d4];
                *(short4*)(frow + d4 * 4)       = make_short4(f2bf(v1.x), f2bf(v1.y), f2bf(v1.z), f2bf(v1.w));
                *(short4*)(frow + 128 + d4 * 4) = make_short4(f2bf(v2.x), f2bf(v2.y), f2bf(v2.z), f2bf(v2.w));
                *(short4*)(frow + 256 + d4 * 4) = make_short4(f2bf(v3.x), f2bf(v3.y), f2bf(v3.z), f2bf(v3.w));
            }
        } else {
            for (int d = s * 4; d < 384; d += 16) *(short4*)(frow + d) = make_short4(0, 0, 0, 0);
        }
    }
    __syncthreads();

    f32x4 acc[8];
#pragma unroll
    for (int c0 = 0; c0 < 256; c0 += 128) {
        mfma_gemm<384, FSTR, 256, true>(feat, W1pk, b1, wave * 16, c0, lane, acc);
        pack_relu<H1STR, false>(acc, h1s, wave * 16, c0, lane);
    }
    __syncthreads();
    mfma_gemm<256, H1STR, 128, true>(h1s, W2pk, b2, wave * 16, 0, lane, acc);
    {
        const int l15 = lane & 15, lg = lane >> 4;
#pragma unroll
        for (int f = 0; f < 8; ++f)
#pragma unroll
            for (int i = 0; i < 4; ++i) {
                const int n = n0 + wave * 16 + lg * 4 + i;
                if (n < N)
                    out[(size_t)n * 128 + f * 16 + l15] = fmaxf(acc[f][i], 0.0f);
            }
    }
}

// ===========================================================================
extern "C" void kernel_launch(void* const* d_in, const int* in_sizes, int n_in,
                              void* d_out, int out_size, void* d_ws, size_t ws_size,
                              hipStream_t stream)
{
    const float* x    = (const float*)d_in[0];
    const int*   eidx = (const int*)d_in[1];
    const float* ea   = (const float*)d_in[2];

    const float* c1_eW1 = (const float*)d_in[3];
    const float* c1_eb1 = (const float*)d_in[4];
    const float* c1_eW2 = (const float*)d_in[5];
    const float* c1_eb2 = (const float*)d_in[6];
    const float* c1_lW1 = (const float*)d_in[7];
    const float* c1_lb1 = (const float*)d_in[8];
    const float* c1_lW2 = (const float*)d_in[9];
    const float* c1_lb2 = (const float*)d_in[10];

    const float* c2_eW1 = (const float*)d_in[11];
    const float* c2_eb1 = (const float*)d_in[12];
    const float* c2_eW2 = (const float*)d_in[13];
    const float* c2_eb2 = (const float*)d_in[14];
    const float* c2_lW1 = (const float*)d_in[15];
    const float* c2_lb1 = (const float*)d_in[16];
    const float* c2_lW2 = (const float*)d_in[17];
    const float* c2_lb2 = (const float*)d_in[18];

    const float* c3_eW1 = (const float*)d_in[19];
    const float* c3_eb1 = (const float*)d_in[20];
    const float* c3_eW2 = (const float*)d_in[21];
    const float* c3_eb2 = (const float*)d_in[22];
    const float* c3_lW1 = (const float*)d_in[23];
    const float* c3_lb1 = (const float*)d_in[24];
    const float* c3_lW2 = (const float*)d_in[25];
    const float* c3_lb2 = (const float*)d_in[26];

    const float* fus_W1 = (const float*)d_in[27];
    const float* fus_b1 = (const float*)d_in[28];
    const float* fus_W2 = (const float*)d_in[29];
    const float* fus_b2 = (const float*)d_in[30];

    const int N = in_sizes[0] / 32;   // 25000
    const int E = in_sizes[1] / 2;    // 400000
    const int* srcI = eidx;
    const int* dstI = eidx + E;

    const size_t NP = (size_t)N * 128;
    float* ws  = (float*)d_ws;
    float* x1  = ws;
    float* x2  = x1 + NP;
    float* x3  = x2 + NP;
    float* agg = x3 + NP;
    float* sq  = agg + NP;
    float* eaS = sq + N;
    int* cursor = (int*)(eaS + (size_t)E * 4);
    int* sSrc   = cursor + 25024;
    int* sDst   = sSrc + E;
    short* uB   = (short*)(sDst + E);
    short* vB   = uB + NP;
    short* wpk  = vB + NP;

    // packed-weight offsets (shorts)
    short* e1Wd = wpk + 0;        // KIN 32  KP 32
    short* e1Wb = wpk + 4096;     // KIN 32  KP 32
    short* e1Wp = wpk + 8192;     // KIN 38  KP 64  (p + e1,e2,ea)
    short* e1W2 = wpk + 16384;    // KIN 128 KP 128
    short* e2Wd = wpk + 32768;    // KIN 128 KP 128
    short* e2Wb = wpk + 49152;
    short* e2Wp = wpk + 65536;    // KIN 134 KP 160
    short* e2W2 = wpk + 86016;
    short* e3Wd = wpk + 102400;
    short* e3Wb = wpk + 118784;
    short* e3Wp = wpk + 135168;
    short* e3W2 = wpk + 155648;
    short* n1W1 = wpk + 172032;   // KIN 160 KP 160
    short* n1W2 = wpk + 192512;
    short* n2W1 = wpk + 208896;   // KIN 256 KP 256
    short* n2W2 = wpk + 241664;
    short* n3W1 = wpk + 258048;
    short* n3W2 = wpk + 290816;
    short* fW1  = wpk + 307200;   // KIN 384 NOUT 256
    short* fW2  = wpk + 405504;   // KIN 256
    const int packTotal = 438272;

    PackJobs pj;
    const float* pw[NPACK] = {
        c1_eW1, c1_eW1 + 32 * 128, c1_eW1 + 64 * 128, c1_eW2,
        c2_eW1, c2_eW1 + 128 * 128, c2_eW1 + 256 * 128, c2_eW2,
        c3_eW1, c3_eW1 + 128 * 128, c3_eW1 + 256 * 128, c3_eW2,
        c1_lW1, c1_lW2, c2_lW1, c2_lW2, c3_lW1, c3_lW2,
        fus_W1, fus_W2};
    const float* ps[NPACK] = {
        c1_eW1 + 32 * 128, nullptr, nullptr, nullptr,
        c2_eW1 + 128 * 128, nullptr, nullptr, nullptr,
        c3_eW1 + 128 * 128, nullptr, nullptr, nullptr,
        nullptr, nullptr, nullptr, nullptr, nullptr, nullptr,
        nullptr, nullptr};
    const int pk_kin[NPACK]  = {32, 32, 38, 128, 128, 128, 134, 128,
                                128, 128, 134, 128, 160, 128, 256, 128, 256, 128,
                                384, 256};
    const int pk_nout[NPACK] = {128, 128, 128, 128, 128, 128, 128, 128,
                                128, 128, 128, 128, 128, 128, 128, 128, 128, 128,
                                256, 128};
    const int pk_end[NPACK]  = {4096, 8192, 16384, 32768, 49152, 65536, 86016, 102400,
                                118784, 135168, 155648, 172032, 192512, 208896, 241664,
                                258048, 290816, 307200, 405504, 438272};
    for (int i = 0; i < NPACK; ++i) {
        pj.W[i] = pw[i]; pj.Wsub[i] = ps[i];
        pj.KIN[i] = pk_kin[i]; pj.NOUT[i] = pk_nout[i]; pj.end[i] = pk_end[i];
    }
    pack_all<<<(packTotal + 255) / 256, 256, 0, stream>>>(pj, wpk, packTotal);

    // ---- sort edges by dst ----
    const int eblk = (E + 255) / 256;
    hipMemsetAsync(cursor, 0, 25024 * sizeof(int), stream);
    hist_kernel<<<eblk, 256, 0, stream>>>(dstI, cursor, E);
    scan_kernel<<<1, 1024, 0, stream>>>(cursor, N);
    scatter_kernel<<<eblk, 256, 0, stream>>>(srcI, dstI, ea, cursor, sSrc, sDst, eaS, E);

    const int eblocks = (E + 63) / 64;
    const int nblocks = (N + 63) / 64;
    const int fblocks = (N + 31) / 32;
    const int swzQ = eblocks / 8, swzR = eblocks % 8;
    const size_t aggBytes = NP * sizeof(float);

    // ---- layer 1 (FIN=32) ----
    uv_pre<32, 40><<<nblocks, 256, 0, stream>>>(x, e1Wd, c1_eb1, e1Wb, uB, vB, sq, N);
    hipMemsetAsync(agg, 0, aggBytes, stream);
    edge_conv3<32, 64, 72><<<eblocks, 256, 0, stream>>>(
        x, sSrc, sDst, eaS, sq, uB, vB, e1Wp, e1W2, c1_eb2, agg, E, swzQ, swzR);
    node_mfma<32, 160, 168, false><<<nblocks, 256, 0, stream>>>(
        x, agg, n1W1, c1_lb1, n1W2, c1_lb2, x1, N);

    // ---- layer 2 (FIN=128, residual) ----
    uv_pre<128, 136><<<nblocks, 256, 0, stream>>>(x1, e2Wd, c2_eb1, e2Wb, uB, vB, sq, N);
    hipMemsetAsync(agg, 0, aggBytes, stream);
    edge_conv3<128, 160, 168><<<eblocks, 256, 0, stream>>>(
        x1, sSrc, sDst, eaS, sq, uB, vB, e2Wp, e2W2, c2_eb2, agg, E, swzQ, swzR);
    node_mfma<128, 256, 264, true><<<nblocks, 256, 0, stream>>>(
        x1, agg, n2W1, c2_lb1, n2W2, c2_lb2, x2, N);

    // ---- layer 3 (FIN=128, residual) ----
    uv_pre<128, 136><<<nblocks, 256, 0, stream>>>(x2, e3Wd, c3_eb1, e3Wb, uB, vB, sq, N);
    hipMemsetAsync(agg, 0, aggBytes, stream);
    edge_conv3<128, 160, 168><<<eblocks, 256, 0, stream>>>(
        x2, sSrc, sDst, eaS, sq, uB, vB, e3Wp, e3W2, c3_eb2, agg, E, swzQ, swzR);
    node_mfma<128, 256, 264, true><<<nblocks, 256, 0, stream>>>(
        x2, agg, n3W1, c3_lb1, n3W2, c3_lb2, x3, N);

    // ---- fusion ----
    fusion_mfma<<<fblocks, 128, 0, stream>>>(
        x1, x2, x3, fW1, fus_b1, fW2, fus_b2, (float*)d_out, N);
}